// Round 3
// baseline (128.586 us; speedup 1.0000x reference)
//
#include <hip/hip_runtime.h>

#define HH 256
#define WW 256
#define NPIX (HH * WW)

// The network collapses algebraically:
//  - FPS always selects point 0 (dist[0]=0 is the persistent argmin) -> 500
//    identical selected points.
//  - All rows through the pointnet are identical, so the dense BatchNorms
//    (axes=(0,)) output exactly their beta: h=relu(be4), then relu(be5).
//  - feats (all rows equal) = relu(be5) @ Wd3^T + bd3  =: feats0
//  - out[c,p] = Ws[c,:6] . pc[p] + (bs[c] + Ws[c,6:] . feats0)  inside box,
//    0 outside.  pc = [ invK @ (u+.5, v+.5, 1) * z, rgb ].
//
// setup_kernel: invert intrinsic (f64), feats0 (128-vec GEMV), const80.
//   ws[0..8] = invK row-major, ws[16..95] = const80.
__global__ __launch_bounds__(512) void setup_kernel(
    const float* __restrict__ intrinsic,
    const float* __restrict__ be5,
    const float* __restrict__ Wd3,
    const float* __restrict__ bd3,
    const float* __restrict__ Ws,
    const float* __restrict__ bs,
    float* __restrict__ ws) {
    __shared__ float part[512];
    __shared__ float feats0[128];
    int t = threadIdx.x;
    if (t == 0) {
        double a = intrinsic[0], b = intrinsic[1], c = intrinsic[2];
        double d = intrinsic[3], e = intrinsic[4], f = intrinsic[5];
        double g = intrinsic[6], h = intrinsic[7], i = intrinsic[8];
        double det = a*(e*i - f*h) - b*(d*i - f*g) + c*(d*h - e*g);
        double inv[9] = {
            (e*i - f*h), -(b*i - c*h),  (b*f - c*e),
           -(d*i - f*g),  (a*i - c*g), -(a*f - c*d),
            (d*h - e*g), -(a*h - b*g),  (a*e - b*d)
        };
        for (int m = 0; m < 9; ++m) ws[m] = (float)(inv[m] / det);
    }
    // feats0[j] = bd3[j] + sum_k relu(be5[k]) * Wd3[j*256+k]
    // 512 threads = 128 j  x  4 k-chunks of 64; float4 loads (16/thread).
    int j = t & 127;
    int ck = t >> 7;              // 0..3
    const float4* w4 = (const float4*)(Wd3 + j * 256 + ck * 64);
    float acc = 0.0f;
    #pragma unroll
    for (int q = 0; q < 16; ++q) {
        float4 w = w4[q];
        int k0 = ck * 64 + q * 4;
        acc = fmaf(fmaxf(be5[k0 + 0], 0.0f), w.x, acc);
        acc = fmaf(fmaxf(be5[k0 + 1], 0.0f), w.y, acc);
        acc = fmaf(fmaxf(be5[k0 + 2], 0.0f), w.z, acc);
        acc = fmaf(fmaxf(be5[k0 + 3], 0.0f), w.w, acc);
    }
    part[t] = acc;
    __syncthreads();
    if (ck == 0)
        feats0[j] = bd3[j] + part[j] + part[j + 128] + part[j + 256] + part[j + 384];
    __syncthreads();
    // const80[c] = bs[c] + sum_j feats0[j] * Ws[c*134 + 6 + j]
    // 320 threads = 80 c x 4 j-chunks of 32.
    if (t < 320) {
        int cc = t >> 2, s = t & 3;
        float a2 = 0.0f;
        #pragma unroll
        for (int q = 0; q < 32; ++q) {
            int jj = s * 32 + q;
            a2 = fmaf(feats0[jj], Ws[cc * 134 + 6 + jj], a2);
        }
        part[t] = a2;
    }
    __syncthreads();
    if (t < 80)
        ws[16 + t] = bs[t] + part[4 * t] + part[4 * t + 1] + part[4 * t + 2] + part[4 * t + 3];
}

// Main: block = one image row (256 px). Thread t owns pixel-group
// gi = t>>2 (4 consecutive px) and channel-quarter q = t&3 (20 channels).
// float4 stores: 20 per thread, fully coalesced.
__global__ __launch_bounds__(256) void seg_kernel(
    const float* __restrict__ rgb, const float* __restrict__ depth,
    const int* __restrict__ box,
    const float* __restrict__ Ws,
    const float* __restrict__ ws, float* __restrict__ out) {
    __shared__ float sW[80][6];
    __shared__ float sC[80];
    __shared__ float sik[9];
    int t = threadIdx.x;
    for (int i = t; i < 480; i += 256) sW[i / 6][i % 6] = Ws[(i / 6) * 134 + (i % 6)];
    if (t < 80) sC[t] = ws[16 + t];
    if (t >= 96 && t < 105) sik[t - 96] = ws[t - 96];
    __syncthreads();

    int x1 = box[0], y1 = box[1], x2 = box[2], y2 = box[3];
    int row = blockIdx.x;          // 0..255
    int gi  = t >> 2;              // 0..63
    int q   = t & 3;               // channel quarter
    int col0 = gi * 4;
    int p0 = row * WW + col0;

    // per-pixel point coords (q0..q2) + rgb (q3..q5)
    float4 z4 = *(const float4*)(depth + p0);
    float4 r0 = *(const float4*)(rgb + p0 * 3);
    float4 r1 = *(const float4*)(rgb + p0 * 3 + 4);
    float4 r2 = *(const float4*)(rgb + p0 * 3 + 8);
    float zz[4] = {z4.x, z4.y, z4.z, z4.w};
    float rr[12] = {r0.x, r0.y, r0.z, r0.w, r1.x, r1.y, r1.z, r1.w,
                    r2.x, r2.y, r2.z, r2.w};

    float P[4][6];
    bool inb[4];
    float v = (float)(row - x1) + 0.5f;    // box-relative row coord
    bool rowin = (row >= x1 && row < x2);
    #pragma unroll
    for (int i = 0; i < 4; ++i) {
        int col = col0 + i;
        inb[i] = rowin && (col >= y1 && col < y2);
        float u = (float)(col - y1) + 0.5f;
        float z = zz[i];
        P[i][0] = (u * sik[0] + v * sik[1] + sik[2]) * z;
        P[i][1] = (u * sik[3] + v * sik[4] + sik[5]) * z;
        P[i][2] = (u * sik[6] + v * sik[7] + sik[8]) * z;
        P[i][3] = rr[i * 3 + 0];
        P[i][4] = rr[i * 3 + 1];
        P[i][5] = rr[i * 3 + 2];
    }

    int cbase = q * 20;
    #pragma unroll 4
    for (int k = 0; k < 20; ++k) {
        int c = cbase + k;
        float w0 = sW[c][0], w1 = sW[c][1], w2 = sW[c][2];
        float w3 = sW[c][3], w4 = sW[c][4], w5 = sW[c][5];
        float cc = sC[c];
        float val[4];
        #pragma unroll
        for (int i = 0; i < 4; ++i) {
            float a = cc;
            a = fmaf(w0, P[i][0], a);
            a = fmaf(w1, P[i][1], a);
            a = fmaf(w2, P[i][2], a);
            a = fmaf(w3, P[i][3], a);
            a = fmaf(w4, P[i][4], a);
            a = fmaf(w5, P[i][5], a);
            val[i] = inb[i] ? a : 0.0f;
        }
        *(float4*)(out + c * NPIX + p0) = make_float4(val[0], val[1], val[2], val[3]);
    }
}

extern "C" void kernel_launch(void* const* d_in, const int* in_sizes, int n_in,
                              void* d_out, int out_size, void* d_ws, size_t ws_size,
                              hipStream_t stream) {
    const float* rgb       = (const float*)d_in[0];
    const float* depth     = (const float*)d_in[1];
    const float* intrinsic = (const float*)d_in[2];
    const int*   box       = (const int*)d_in[3];
    const float* be5       = (const float*)d_in[23];
    const float* Wd3       = (const float*)d_in[24];
    const float* bd3       = (const float*)d_in[25];
    const float* Ws        = (const float*)d_in[26];
    const float* bs        = (const float*)d_in[27];
    float* ws  = (float*)d_ws;
    float* out = (float*)d_out;

    setup_kernel<<<1, 512, 0, stream>>>(intrinsic, be5, Wd3, bd3, Ws, bs, ws);
    seg_kernel<<<256, 256, 0, stream>>>(rgb, depth, box, Ws, ws, out);
}